// Round 6
// baseline (655.209 us; speedup 1.0000x reference)
//
#include <hip/hip_runtime.h>

typedef unsigned short u16;
typedef short short8 __attribute__((ext_vector_type(8)));
typedef short short4v __attribute__((ext_vector_type(4)));
typedef float floatx4 __attribute__((ext_vector_type(4)));

#define SQ 2048
#define NH 16
#define HD 128
#define RD 64
#define NB 2
#define LDKV 5120
#define LDQ 3072

// padded LDS strides (multiples of 8 u16 to keep 16B alignment)
#define LKC 136
#define LKR 72
#define LVT 72

#if __has_builtin(__builtin_amdgcn_mfma_f32_16x16x16_bf16)
#define MFMA16K16(va, vb, vc) __builtin_amdgcn_mfma_f32_16x16x16_bf16(va, vb, vc, 0, 0, 0)
#else
#define MFMA16K16(va, vb, vc) __builtin_amdgcn_mfma_f32_16x16x16bf16_1k(va, vb, vc, 0, 0, 0)
#endif

__device__ __forceinline__ float bf2f(u16 u) {
  union { unsigned u; float f; } v; v.u = ((unsigned)u) << 16; return v.f;
}
__device__ __forceinline__ u16 f2bf(float f) {
  union { float f; unsigned u; } v; v.f = f;
  return (u16)((v.u + 0x7FFFu + ((v.u >> 16) & 1u)) >> 16);
}
__device__ __forceinline__ void gll16(const u16* g, u16* l) {
  __builtin_amdgcn_global_load_lds((const __attribute__((address_space(1))) void*)g,
                                   (__attribute__((address_space(3))) void*)l, 16, 0, 0);
}

// ---- x (f32) -> bf16, vectorized ----
__global__ __launch_bounds__(256) void convert_x(const float* __restrict__ src,
                                                 u16* __restrict__ dst, int n4) {
  const int i = blockIdx.x * 256 + threadIdx.x;
  if (i >= n4) return;
  const floatx4 v = *(const floatx4*)(src + 4 * (size_t)i);
  short4v o;
  o.x = (short)f2bf(v.x); o.y = (short)f2bf(v.y);
  o.z = (short)f2bf(v.z); o.w = (short)f2bf(v.w);
  *(short4v*)(dst + 4 * (size_t)i) = o;
}

// ---- all 8 biases (f32) -> concatenated bf16 slots ----
__global__ __launch_bounds__(256) void convert_biases(
    const float* b0, const float* b1, const float* b2, const float* b3,
    const float* b4, const float* b5, const float* b6, const float* b7,
    u16* __restrict__ bc) {
  const int i = blockIdx.x * 256 + threadIdx.x;
  if (i >= 12288) return;
  float v;
  if      (i < 512)   v = b0[i];
  else if (i < 2048)  v = b1[i - 512];
  else if (i < 4096)  v = b2[i - 2048];
  else if (i < 6144)  v = b3[i - 4096];
  else if (i < 7168)  v = b4[i - 6144];
  else if (i < 9216)  v = b5[i - 7168];
  else if (i < 10240) v = b6[i - 9216];
  else                v = b7[i - 10240];
  bc[i] = f2bf(v);
}

// ---- merged weight transposes: 8 segments, in[R][C] f32 -> out[C][R] bf16 ----
struct TSeg { const float* in; u16* out; int R, C, bstart; };
struct TArgs { TSeg s[8]; };

__global__ __launch_bounds__(256) void transpose_all(TArgs a) {
  __shared__ u16 tile[32][33];
  const int bx = blockIdx.x;
  int si = 0;
#pragma unroll
  for (int i = 1; i < 8; i++) si = (bx >= a.s[i].bstart) ? i : si;
  const float* in = a.s[si].in;
  u16* out = a.s[si].out;
  const int R = a.s[si].R, C = a.s[si].C;
  const int local = bx - a.s[si].bstart;
  const int nbx = C / 32;
  const int c0 = (local % nbx) * 32, r0 = (local / nbx) * 32;
  const int x = threadIdx.x & 31, y = threadIdx.x >> 5;
#pragma unroll
  for (int i = 0; i < 32; i += 8)
    tile[y + i][x] = f2bf(in[(size_t)(r0 + y + i) * C + c0 + x]);
  __syncthreads();
#pragma unroll
  for (int i = 0; i < 32; i += 8)
    out[(size_t)(c0 + y + i) * R + r0 + x] = tile[x][y + i];
}

// ---- V (cols 2048..4095 of KV) -> Vt [B,H,HD,S] ----
__global__ __launch_bounds__(256) void transpose_v(const u16* __restrict__ KV,
                                                   u16* __restrict__ Vt) {
  __shared__ u16 tile[32][33];
  const int bh = blockIdx.z, b = bh >> 4, hh = bh & 15;
  const u16* pin = KV + (size_t)b * SQ * LDKV + 2048 + (size_t)hh * HD;
  u16* pout = Vt + (size_t)bh * HD * SQ;
  const int s0 = blockIdx.x * 32, d0 = blockIdx.y * 32;
  const int x = threadIdx.x & 31, y = threadIdx.x >> 5;
#pragma unroll
  for (int i = 0; i < 32; i += 8)
    tile[y + i][x] = pin[(size_t)(s0 + y + i) * LDKV + d0 + x];
  __syncthreads();
#pragma unroll
  for (int i = 0; i < 32; i += 8)
    pout[(size_t)(d0 + y + i) * SQ + s0 + x] = tile[x][y + i];
}

// ---- RoPE (both Kr and Qr in one launch, blockIdx.y selects) ----
__global__ __launch_bounds__(256) void rope2(u16* __restrict__ KV, u16* __restrict__ Qb) {
  const int i = blockIdx.x * 256 + threadIdx.x;
  if (i >= NB * SQ * NH * 32) return;
  u16* buf = blockIdx.y ? Qb : KV;
  const int ld = blockIdx.y ? LDQ : LDKV;
  const int coloff = blockIdx.y ? 2048 : 4096;
  const int j = i & 31;
  const int hh = (i >> 5) & 15;
  const int row = i >> 9;
  const int s = row & (SQ - 1);
  u16* p = buf + (size_t)row * ld + coloff + hh * RD + 2 * j;
  const float x1 = bf2f(p[0]), x2 = bf2f(p[1]);
  const float inv = exp2f(-(float)j * 0.41524101186092031f);  // 10000^(-j/32)
  const float ang = (float)s * inv;
  float sn, cs;
  sincosf(ang, &sn, &cs);
  p[0] = f2bf(x1 * cs - x2 * sn);
  p[1] = f2bf(x1 * sn + x2 * cs);
}

// ---- C[M=4096,N] = A[.,K](lda) * Bt[N,K]^T + bias; out bf16(ldc) or f32 ----
__global__ __launch_bounds__(256) void gemm_bt(const u16* __restrict__ A, int lda,
                                               const u16* __restrict__ Bt,
                                               const u16* __restrict__ bias,
                                               void* __restrict__ Cout, int ldc,
                                               int wf32, int N, int K) {
  __shared__ __align__(16) u16 lA[128 * 32];
  __shared__ __align__(16) u16 lB[128 * 32];
  const int t = threadIdx.x;
  const int lane = t & 63, w = t >> 6;
  const int wm = w & 1, wn = w >> 1;
  const int m0 = blockIdx.y * 128, n0 = blockIdx.x * 128;
  const int srow = t >> 2, scol = (t & 3) * 8;
  const u16* gA = A + (size_t)(m0 + srow) * lda + scol;
  const u16* gB = Bt + (size_t)(n0 + srow) * K + scol;
  u16* lA0 = lA + (16 * w) * 32;
  u16* lA1 = lA + (64 + 16 * w) * 32;
  u16* lB0 = lB + (16 * w) * 32;
  u16* lB1 = lB + (64 + 16 * w) * 32;
  const int lane_m = lane & 15, lane_k = (lane >> 4) * 8;
  floatx4 acc[4][4] = {};
  for (int k0 = 0; k0 < K; k0 += 32) {
    gll16(gA + k0, lA0);
    gll16(gA + (size_t)64 * lda + k0, lA1);
    gll16(gB + k0, lB0);
    gll16(gB + (size_t)64 * K + k0, lB1);
    __syncthreads();
    short8 af[4], bf[4];
#pragma unroll
    for (int i = 0; i < 4; i++)
      af[i] = *(const short8*)(lA + (wm * 64 + i * 16 + lane_m) * 32 + lane_k);
#pragma unroll
    for (int i = 0; i < 4; i++)
      bf[i] = *(const short8*)(lB + (wn * 64 + i * 16 + lane_m) * 32 + lane_k);
#pragma unroll
    for (int mi = 0; mi < 4; mi++)
#pragma unroll
      for (int ni = 0; ni < 4; ni++)
        acc[mi][ni] = __builtin_amdgcn_mfma_f32_16x16x32_bf16(af[mi], bf[ni], acc[mi][ni], 0, 0, 0);
    __syncthreads();
  }
  const int quad = lane >> 4;
#pragma unroll
  for (int ni = 0; ni < 4; ni++) {
    const int col = n0 + wn * 64 + ni * 16 + lane_m;
    const float bv = bf2f(bias[col]);
#pragma unroll
    for (int mi = 0; mi < 4; mi++) {
      const int row = m0 + wm * 64 + mi * 16 + quad * 4;
      if (wf32) {
        float* pc = (float*)Cout + (size_t)row * ldc + col;
#pragma unroll
        for (int r = 0; r < 4; r++)
          pc[(size_t)r * ldc] = acc[mi][ni][r] + bv;
      } else {
        u16* pc = (u16*)Cout + (size_t)row * ldc + col;
#pragma unroll
        for (int r = 0; r < 4; r++)
          pc[(size_t)r * ldc] = f2bf(acc[mi][ni][r] + bv);
      }
    }
  }
}

// ---- flash attention: grid (32, 32) = (qt, b*16+h); 4 waves, 16 q-rows each ----
// Transposed-score scheme: S^T = K*Q^T (C-layout: lane owns q=lane&15, k=quad*4+r);
// softmax per-lane + 2 cross-quad shuffles; PV consumes P from registers via
// 16x16x16 MFMA (O accumulated transposed). No P LDS round-trip.
__global__ __launch_bounds__(256, 3) void flash_attn(const u16* __restrict__ Q,
                                                     const u16* __restrict__ KV,
                                                     const u16* __restrict__ Vt,
                                                     u16* __restrict__ Ctx) {
  __shared__ __align__(16) u16 lKc[64 * LKC];
  __shared__ __align__(16) u16 lKr[64 * LKR];
  __shared__ __align__(16) u16 lVt[128 * LVT];
  const int t = threadIdx.x, lane = t & 63, w = t >> 6;
  const int qt = 31 - blockIdx.x;  // heavy tiles first
  const int h = blockIdx.y & (NH - 1);
  const int b = blockIdx.y >> 4;
  const int q0 = qt * 64;
  const int lane_m = lane & 15, quad = lane >> 4, lane_k = quad * 8;

  // Q fragments (identical layout as A- or B-operand)
  const int qrow = q0 + 16 * w + lane_m;
  const u16* qcp = Q + (size_t)(b * SQ + qrow) * LDQ + h * HD;
  const u16* qrp = Q + (size_t)(b * SQ + qrow) * LDQ + 2048 + h * RD;
  short8 qfc[4], qfr[2];
#pragma unroll
  for (int ks = 0; ks < 4; ks++) qfc[ks] = *(const short8*)(qcp + ks * 32 + lane_k);
#pragma unroll
  for (int ks = 0; ks < 2; ks++) qfr[ks] = *(const short8*)(qrp + ks * 32 + lane_k);

  floatx4 OT[8] = {};           // O^T[d=db*16+quad*4+r][q=lane_m]
  float mrow = -1e30f, lsum = 0.f;

  const float C2 = 0.10412825525540364f;  // (1/sqrt(192)) * log2(e)

  // staging pointers (incremental)
  const int r16 = t >> 4, c16 = (t & 15) * 8;
  const int r8 = t >> 3, c8 = (t & 7) * 8;
  const u16* pKc = KV + (size_t)b * SQ * LDKV + h * HD + (size_t)r16 * LDKV + c16;
  const u16* pKr = KV + (size_t)b * SQ * LDKV + 4096 + h * RD + (size_t)r8 * LDKV + c8;
  const u16* pVt = Vt + (size_t)(b * NH + h) * HD * SQ + (size_t)r8 * SQ + c8;

  short8 rKc[4], rKr[2], rVt[4];
  auto load_tile = [&]() {
#pragma unroll
    for (int i = 0; i < 4; i++) rKc[i] = *(const short8*)(pKc + (size_t)i * 16 * LDKV);
#pragma unroll
    for (int i = 0; i < 2; i++) rKr[i] = *(const short8*)(pKr + (size_t)i * 32 * LDKV);
#pragma unroll
    for (int i = 0; i < 4; i++) rVt[i] = *(const short8*)(pVt + (size_t)i * 32 * SQ);
  };

  load_tile();
  for (int kt = 0; kt <= qt; kt++) {
    __syncthreads();
#pragma unroll
    for (int i = 0; i < 4; i++) *(short8*)(lKc + (r16 + i * 16) * LKC + c16) = rKc[i];
#pragma unroll
    for (int i = 0; i < 2; i++) *(short8*)(lKr + (r8 + i * 32) * LKR + c8) = rKr[i];
#pragma unroll
    for (int i = 0; i < 4; i++) *(short8*)(lVt + (r8 + i * 32) * LVT + c8) = rVt[i];
    __syncthreads();
    pKc += (size_t)64 * LDKV; pKr += (size_t)64 * LDKV; pVt += 64;
    if (kt < qt) load_tile();  // prefetch overlaps compute

    // S^T = K * Q^T: 4 key-blocks of 16
    float ss[4][4];
#pragma unroll
    for (int n = 0; n < 4; n++) {
      floatx4 a = {0.f, 0.f, 0.f, 0.f};
#pragma unroll
      for (int ks = 0; ks < 4; ks++) {
        const short8 kf = *(const short8*)(lKc + (n * 16 + lane_m) * LKC + ks * 32 + lane_k);
        a = __builtin_amdgcn_mfma_f32_16x16x32_bf16(kf, qfc[ks], a, 0, 0, 0);
      }
#pragma unroll
      for (int ks = 0; ks < 2; ks++) {
        const short8 kf = *(const short8*)(lKr + (n * 16 + lane_m) * LKR + ks * 32 + lane_k);
        a = __builtin_amdgcn_mfma_f32_16x16x32_bf16(kf, qfr[ks], a, 0, 0, 0);
      }
#pragma unroll
      for (int r = 0; r < 4; r++) ss[n][r] = a[r];
    }
    if (kt == qt) {  // causal mask on diagonal tile
#pragma unroll
      for (int n = 0; n < 4; n++)
#pragma unroll
        for (int r = 0; r < 4; r++)
          if (q0 + n * 16 + quad * 4 + r > qrow) ss[n][r] = -1e30f;
    }
    // online softmax: lane owns q=lane_m; reduce across quads (xor 16, 32)
    float m = ss[0][0];
#pragma unroll
    for (int n = 0; n < 4; n++)
#pragma unroll
      for (int r = 0; r < 4; r++) m = fmaxf(m, ss[n][r]);
    m = fmaxf(m, __shfl_xor(m, 16));
    m = fmaxf(m, __shfl_xor(m, 32));
    const float mn = fmaxf(mrow, m);
    const float alpha = exp2f((mrow - mn) * C2);
    mrow = mn;
    float s = 0.f;
#pragma unroll
    for (int n = 0; n < 4; n++)
#pragma unroll
      for (int r = 0; r < 4; r++) {
        ss[n][r] = exp2f((ss[n][r] - mn) * C2);
        s += ss[n][r];
      }
    s += __shfl_xor(s, 16);
    s += __shfl_xor(s, 32);
    lsum = lsum * alpha + s;
#pragma unroll
    for (int db = 0; db < 8; db++)
#pragma unroll
      for (int r = 0; r < 4; r++) OT[db][r] *= alpha;

    // PV: O^T += V^T * P^T, K=16 MFMA, P from registers
#pragma unroll
    for (int n = 0; n < 4; n++) {
      short4v pfrag;
      pfrag.x = (short)f2bf(ss[n][0]);
      pfrag.y = (short)f2bf(ss[n][1]);
      pfrag.z = (short)f2bf(ss[n][2]);
      pfrag.w = (short)f2bf(ss[n][3]);
#pragma unroll
      for (int db = 0; db < 8; db++) {
        const short4v vfrag =
            *(const short4v*)(lVt + (db * 16 + lane_m) * LVT + n * 16 + quad * 4);
        OT[db] = MFMA16K16(vfrag, pfrag, OT[db]);
      }
    }
  }
  const float inv = 1.f / lsum;
  u16* pout = Ctx + (size_t)(b * SQ + qrow) * 2048 + h * HD + quad * 4;
#pragma unroll
  for (int db = 0; db < 8; db++) {
    short4v o;
    o.x = (short)f2bf(OT[db][0] * inv);
    o.y = (short)f2bf(OT[db][1] * inv);
    o.z = (short)f2bf(OT[db][2] * inv);
    o.w = (short)f2bf(OT[db][3] * inv);
    *(short4v*)(pout + db * 16) = o;
  }
}

extern "C" void kernel_launch(void* const* d_in, const int* in_sizes, int n_in,
                              void* d_out, int out_size, void* d_ws, size_t ws_size,
                              hipStream_t stream) {
  (void)in_sizes; (void)n_in; (void)out_size; (void)ws_size;
  const float* x    = (const float*)d_in[0];
  const float* kvdw = (const float*)d_in[2];
  const float* kvdb = (const float*)d_in[3];
  const float* kuw  = (const float*)d_in[4];
  const float* kub  = (const float*)d_in[5];
  const float* vuw  = (const float*)d_in[6];
  const float* vub  = (const float*)d_in[7];
  const float* krw  = (const float*)d_in[8];
  const float* krb  = (const float*)d_in[9];
  const float* qdw  = (const float*)d_in[10];
  const float* qdb  = (const float*)d_in[11];
  const float* quw  = (const float*)d_in[12];
  const float* qub  = (const float*)d_in[13];
  const float* qrw  = (const float*)d_in[14];
  const float* qrb  = (const float*)d_in[15];
  const float* ow   = (const float*)d_in[16];
  const float* ob   = (const float*)d_in[17];

  u16* p = (u16*)d_ws;
  u16* bc   = p;  p += 16384;
  u16* WT1  = p;  p += (size_t)2048 * 2048;  // kvd^T | qd^T
  u16* WT2  = p;  p += (size_t)5120 * 512;   // ku^T|vu^T|kr^T
  u16* WT3  = p;  p += (size_t)3072 * 1536;  // qu^T|qr^T
  u16* Ctx  = WT1;                           // overlays WT1..WT3
  u16* WTo  = p;  p += (size_t)2048 * 2048;  // o^T
  u16* KVQd = p;  p += (size_t)4096 * 2048;  // kv_c|q_c
  u16* Vt   = KVQd;                          // overlays (dead after G3)
  u16* KV   = p;  p += (size_t)4096 * 5120;  // Kc|V|Kr
  u16* Qb   = p;  p += (size_t)4096 * 3072;  // Qc|Qr
  u16* xc   = Qb;                            // overlays Q (dead after G1)

  convert_x<<<dim3(8192), 256, 0, stream>>>(x, xc, 4096 * 2048 / 4);
  convert_biases<<<dim3(48), 256, 0, stream>>>(kvdb, qdb, kub, vub, krb, qub, qrb, ob, bc);

  TArgs ta;
  int bs = 0;
  auto seg = [&](int i, const float* in, u16* out, int R, int C) {
    ta.s[i] = {in, out, R, C, bs};
    bs += (R / 32) * (C / 32);
  };
  seg(0, kvdw, WT1, 2048, 512);
  seg(1, qdw,  WT1 + (size_t)512 * 2048, 2048, 1536);
  seg(2, kuw,  WT2, 512, 2048);
  seg(3, vuw,  WT2 + (size_t)2048 * 512, 512, 2048);
  seg(4, krw,  WT2 + (size_t)4096 * 512, 512, 1024);
  seg(5, quw,  WT3, 1536, 2048);
  seg(6, qrw,  WT3 + (size_t)2048 * 1536, 1536, 1024);
  seg(7, ow,   WTo, 2048, 2048);
  transpose_all<<<dim3(bs), 256, 0, stream>>>(ta);

  auto G = [&](const u16* A, int lda, const u16* Bt, const u16* bias,
               void* Cout, int ldc, int wf32, int N, int K) {
    gemm_bt<<<dim3(N / 128, 4096 / 128), 256, 0, stream>>>(A, lda, Bt, bias, Cout, ldc, wf32, N, K);
  };
  G(xc, 2048, WT1, bc, KVQd, 2048, 0, 2048, 2048);                 // kv_c | q_c
  G(KVQd, 2048, WT2, bc + 2048, KV, LDKV, 0, 5120, 512);           // Kc | V | Kr
  G(KVQd + 512, 2048, WT3, bc + 7168, Qb, LDQ, 0, 3072, 1536);     // Qc | Qr

  rope2<<<dim3(512, 2), 256, 0, stream>>>(KV, Qb);
  transpose_v<<<dim3(SQ / 32, HD / 32, NB * NH), 256, 0, stream>>>(KV, Vt);
  flash_attn<<<dim3(32, 32), 256, 0, stream>>>(Qb, KV, Vt, Ctx);

  G(Ctx, 2048, WTo, bc + 10240, d_out, 2048, 1, 2048, 2048);       // out proj (f32)
}